// Round 8
// baseline (468.879 us; speedup 1.0000x reference)
//
#include <hip/hip_runtime.h>
#include <math.h>
#include <stdint.h>

#define B_ 2
#define S_ 2048
#define H_ 16
#define KVH_ 4
#define HD_ 128
#define NC_ 16
#define CHK_ 128
#define EPS_ 1e-6f
#define GK_ 2048          // K dim of both big GEMMs
#define NT8_ (GK_ / 32)   // 64 K-tiles of 32

typedef __attribute__((ext_vector_type(8))) short short8;   // 8 bf16 (4 VGPR)
typedef __attribute__((ext_vector_type(4))) float f32x4;

// async global->LDS, 16B per lane; LDS dst wave-uniform base + lane*16
#define GLOAD16(gsrc, sdst) \
    __builtin_amdgcn_global_load_lds((const __attribute__((address_space(1))) unsigned int*)(gsrc), \
                                     (__attribute__((address_space(3))) unsigned int*)(sdst), 16, 0, 0)

#define MFMA_B16(a, b, c) __builtin_amdgcn_mfma_f32_16x16x32_bf16((a), (b), (c), 0, 0, 0)

static __device__ __forceinline__ float bf2f(unsigned int u) {
    return __uint_as_float(u << 16);
}

// 8 fp32 -> hi/lo bf16 uint4 pair (truncation split, residual exact)
static __device__ __forceinline__ void pack8(const float* v, uint4& hi, uint4& lo) {
    unsigned int h[4], l[4];
#pragma unroll
    for (int w = 0; w < 4; w++) {
        unsigned int b0 = __float_as_uint(v[2 * w]);
        unsigned int b1 = __float_as_uint(v[2 * w + 1]);
        unsigned int h0 = b0 & 0xFFFF0000u, h1 = b1 & 0xFFFF0000u;
        h[w] = (h0 >> 16) | h1;
        float r0 = v[2 * w] - __uint_as_float(h0);
        float r1 = v[2 * w + 1] - __uint_as_float(h1);
        l[w] = (__float_as_uint(r0) >> 16) | (__float_as_uint(r1) & 0xFFFF0000u);
    }
    hi = make_uint4(h[0], h[1], h[2], h[3]);
    lo = make_uint4(l[0], l[1], l[2], l[3]);
}

// 8 fp32 -> hi/lo short8 MFMA fragments
static __device__ __forceinline__ void split8_frag(const float* p, short8& hi, short8& lo) {
#pragma unroll
    for (int e = 0; e < 8; e++) {
        unsigned int b = __float_as_uint(p[e]);
        unsigned int h = b & 0xFFFF0000u;
        hi[e] = (short)(h >> 16);
        float r = p[e] - __uint_as_float(h);
        lo[e] = (short)(__float_as_uint(r) >> 16);
    }
}

// ------------------------------------------------------------------ RoPE tables
__global__ __launch_bounds__(256) void rope_tables_k(float* __restrict__ cost,
                                                     float* __restrict__ sint) {
    int idx = blockIdx.x * 256 + threadIdx.x;      // S_*64 exact
    int j = idx & 63;
    int s = idx >> 6;
    float inv_freq = powf(10000.0f, -(float)(2 * j) / 128.0f);
    float f = (float)s * inv_freq;
    cost[idx] = cosf(f);
    sint[idx] = sinf(f);
}

// ------------------------------------------------------------------ fused input packer
__global__ __launch_bounds__(256) void split_in_k(
    const float* __restrict__ x,  const float* __restrict__ wq,
    const float* __restrict__ wk, const float* __restrict__ wv,
    unsigned int* __restrict__ xpk,  unsigned int* __restrict__ wqpk,
    unsigned int* __restrict__ wkpk, unsigned int* __restrict__ wvpk)
{
    int g = blockIdx.x * 256 + threadIdx.x;
    const float* in;
    unsigned int* outp;
    int lg;
    if (g < 1048576)      { in = x;  outp = xpk;  lg = g; }
    else if (g < 1572864) { in = wq; outp = wqpk; lg = g - 1048576; }
    else if (g < 1703936) { in = wk; outp = wkpk; lg = g - 1572864; }
    else                  { in = wv; outp = wvpk; lg = g - 1703936; }
    const float* p = in + (size_t)lg * 8;
    float v[8];
    *(float4*)&v[0] = *(const float4*)p;
    *(float4*)&v[4] = *(const float4*)(p + 4);
    uint4 hi, lo;
    pack8(v, hi, lo);
    unsigned int* op = outp + (size_t)lg * 8;
    *(uint4*)op       = hi;
    *(uint4*)(op + 4) = lo;
}

// ------------------------------------------------------------------ plain packer (Wo)
__global__ __launch_bounds__(256) void split_k(const float* __restrict__ in,
                                               unsigned int* __restrict__ outp, int ngrp)
{
    int g = blockIdx.x * 256 + threadIdx.x;
    if (g >= ngrp) return;
    const float* p = in + (size_t)g * 8;
    float x[8];
    *(float4*)&x[0] = *(const float4*)p;
    *(float4*)&x[4] = *(const float4*)(p + 4);
    uint4 hi, lo;
    pack8(x, hi, lo);
    unsigned int* op = outp + (size_t)g * 8;
    *(uint4*)op       = hi;
    *(uint4*)(op + 4) = lo;
}

// ------------------------------------------------------------------ bf16x3 MFMA GEMM, 8-wave pipelined
// BM=256, BN=128, BK=32, 8 waves (4m x 2n), triple-buffered LDS, 2-deep prefetch,
// counted vmcnt(6) per K-tile (never 0 in steady state). EPI=1: fused QKV epilogue.
template <int EPI>
__global__ __launch_bounds__(512, 1) void gemm8_k(
    const char* __restrict__ Apk, const char* __restrict__ W0,
    const char* __restrict__ W1, const char* __restrict__ W2,
    float* __restrict__ Y, int ldY, int nend0, int nend1, int nbx,
    const float* __restrict__ cosT, const float* __restrict__ sinT,
    char* __restrict__ qfo, char* __restrict__ kfo, float* __restrict__ vvo)
{
    __shared__ __attribute__((aligned(16))) char smem[147456];  // 3 x (A 32K | B 16K)

    int nwg = gridDim.x;
    int bid = blockIdx.x;
    int swz = (bid & 7) * (nwg >> 3) + (bid >> 3);   // XCD-bijective (nwg % 8 == 0)
    int by = swz / nbx, bx = swz % nbx;
    const int m0 = by * 256, n0 = bx * 128;

    const char* Wsel;
    int nw;
    if (n0 < nend0)      { Wsel = W0; nw = n0; }
    else if (n0 < nend1) { Wsel = W1; nw = n0 - nend0; }
    else                 { Wsel = W2; nw = n0 - nend1; }

    const int tid = threadIdx.x;
    const int lane = tid & 63;
    const int wv = tid >> 6;            // wave 0..7
    const int wm = wv >> 1, wn = wv & 1;

    // staging: A 256 rows (4 loads/wave), B 128 rows (2 loads/wave); src slot pre-XOR'd by row&7
    const int r8 = lane >> 3, sl = lane & 7;
    const char* asrc[4];
    const char* bsrc[2];
    int adst[4], bdst[2];
#pragma unroll
    for (int i = 0; i < 4; i++) {
        int rowA = wv * 32 + i * 8 + r8;
        asrc[i] = Apk + (size_t)(m0 + rowA) * (GK_ * 4) + (size_t)((sl ^ (rowA & 7)) * 16);
        adst[i] = wv * 4096 + i * 1024;
    }
#pragma unroll
    for (int j = 0; j < 2; j++) {
        int rowB = wv * 16 + j * 8 + r8;
        bsrc[j] = Wsel + (size_t)(nw + rowB) * (GK_ * 4) + (size_t)((sl ^ (rowB & 7)) * 16);
        bdst[j] = 32768 + wv * 2048 + j * 1024;
    }

    // fragment read offsets (same swizzle algebra as the proven 128^2 kernel)
    const int lrow = lane & 15, lg = lane >> 4, lc7 = lane & 7;
    int aoff[4], boff[4];
#pragma unroll
    for (int f = 0; f < 4; f++) {
        aoff[f] = (wm * 64 + f * 16 + lrow) * 128 + (((lg << 1) ^ lc7) << 4);
        boff[f] = 32768 + (wn * 64 + f * 16 + lrow) * 128 + (((lg << 1) ^ lc7) << 4);
    }

    f32x4 acc[4][4];
#pragma unroll
    for (int i = 0; i < 4; i++)
#pragma unroll
        for (int j = 0; j < 4; j++) acc[i][j] = (f32x4)(0.f);

    // prologue: stage T0 -> buf0, T1 -> buf1 (6 loads each), wait T0, barrier
#pragma unroll
    for (int i = 0; i < 4; i++) GLOAD16(asrc[i], smem + adst[i]);
#pragma unroll
    for (int j = 0; j < 2; j++) GLOAD16(bsrc[j], smem + bdst[j]);
#pragma unroll
    for (int i = 0; i < 4; i++) GLOAD16(asrc[i] + 128, smem + 49152 + adst[i]);
#pragma unroll
    for (int j = 0; j < 2; j++) GLOAD16(bsrc[j] + 128, smem + 49152 + bdst[j]);
    asm volatile("s_waitcnt vmcnt(6)" ::: "memory");
    __builtin_amdgcn_s_barrier();
    __builtin_amdgcn_sched_barrier(0);

#pragma unroll 1
    for (int kt = 0; kt < NT8_; ++kt) {
        const char* sb = smem + (kt % 3) * 49152;
        char* stp = smem + ((kt + 2) % 3) * 49152;
        const size_t koff = (size_t)(kt + 2) * 128;
        const bool st = (kt + 2 < NT8_);

        // ---------------- phase 0: issue 3 stage-loads, read B + A0/A1, 24 MFMA
        if (st) {
            GLOAD16(asrc[0] + koff, stp + adst[0]);
            GLOAD16(asrc[1] + koff, stp + adst[1]);
            GLOAD16(asrc[2] + koff, stp + adst[2]);
        }
        short8 bh[4], bl[4];
#pragma unroll
        for (int f = 0; f < 4; f++) {
            bh[f] = *(const short8*)(sb + boff[f]);
            bl[f] = *(const short8*)(sb + (boff[f] ^ 16));
        }
        short8 a0h = *(const short8*)(sb + aoff[0]);
        short8 a0l = *(const short8*)(sb + (aoff[0] ^ 16));
        short8 a1h = *(const short8*)(sb + aoff[1]);
        short8 a1l = *(const short8*)(sb + (aoff[1] ^ 16));
        __builtin_amdgcn_s_setprio(1);
#pragma unroll
        for (int j = 0; j < 4; j++) {
            acc[0][j] = MFMA_B16(a0h, bh[j], acc[0][j]);
            acc[0][j] = MFMA_B16(a0h, bl[j], acc[0][j]);
            acc[0][j] = MFMA_B16(a0l, bh[j], acc[0][j]);
            acc[1][j] = MFMA_B16(a1h, bh[j], acc[1][j]);
            acc[1][j] = MFMA_B16(a1h, bl[j], acc[1][j]);
            acc[1][j] = MFMA_B16(a1l, bh[j], acc[1][j]);
        }
        __builtin_amdgcn_s_setprio(0);
        __builtin_amdgcn_s_barrier();

        // ---------------- phase 1: issue 3 stage-loads, read A2/A3, 24 MFMA
        if (st) {
            GLOAD16(asrc[3] + koff, stp + adst[3]);
            GLOAD16(bsrc[0] + koff, stp + bdst[0]);
            GLOAD16(bsrc[1] + koff, stp + bdst[1]);
        }
        short8 a2h = *(const short8*)(sb + aoff[2]);
        short8 a2l = *(const short8*)(sb + (aoff[2] ^ 16));
        short8 a3h = *(const short8*)(sb + aoff[3]);
        short8 a3l = *(const short8*)(sb + (aoff[3] ^ 16));
        __builtin_amdgcn_s_setprio(1);
#pragma unroll
        for (int j = 0; j < 4; j++) {
            acc[2][j] = MFMA_B16(a2h, bh[j], acc[2][j]);
            acc[2][j] = MFMA_B16(a2h, bl[j], acc[2][j]);
            acc[2][j] = MFMA_B16(a2l, bh[j], acc[2][j]);
            acc[3][j] = MFMA_B16(a3h, bh[j], acc[3][j]);
            acc[3][j] = MFMA_B16(a3h, bl[j], acc[3][j]);
            acc[3][j] = MFMA_B16(a3l, bh[j], acc[3][j]);
        }
        __builtin_amdgcn_s_setprio(0);
        // tile boundary: retire next tile's loads (counted), then one barrier
        if (kt < NT8_ - 2) {
            asm volatile("s_waitcnt vmcnt(6)" ::: "memory");
        } else if (kt == NT8_ - 2) {
            asm volatile("s_waitcnt vmcnt(0)" ::: "memory");
        }
        __builtin_amdgcn_s_barrier();
        __builtin_amdgcn_sched_barrier(0);
    }

    if (EPI == 0) {
        // plain fp32 store; C/D: col = lane&15, row = (lane>>4)*4 + reg
#pragma unroll
        for (int i = 0; i < 4; i++) {
            int r0 = m0 + wm * 64 + i * 16 + lg * 4;
#pragma unroll
            for (int j = 0; j < 4; j++) {
                int cc = n0 + wn * 64 + j * 16 + lrow;
                f32x4 v = acc[i][j];
                Y[(size_t)(r0 + 0) * ldY + cc] = v[0];
                Y[(size_t)(r0 + 1) * ldY + cc] = v[1];
                Y[(size_t)(r0 + 2) * ldY + cc] = v[2];
                Y[(size_t)(r0 + 3) * ldY + cc] = v[3];
            }
        }
    } else {
        // fused QKV epilogue via 128KB Ct in LDS (all buffers dead after final barrier)
        float* Ct = (float*)smem;      // [256][128] fp32
#pragma unroll
        for (int i = 0; i < 4; i++) {
            int r = wm * 64 + i * 16 + lg * 4;
#pragma unroll
            for (int j = 0; j < 4; j++) {
                int ccol = wn * 64 + j * 16 + lrow;
#pragma unroll
                for (int rr = 0; rr < 4; rr++)
                    Ct[(r + rr) * 128 + ccol] = acc[i][j][rr];
            }
        }
        __syncthreads();
        if (n0 < 2560) {
            // q or k head: RoPE + elu(+1) + pack hi/lo
            const int isq = (n0 < 2048) ? 1 : 0;
            const int hh = isq ? (n0 >> 7) : ((n0 - 2048) >> 7);
            char* basep = isq ? qfo : kfo;
            const int bstride = (isq ? H_ : KVH_) * S_;
#pragma unroll
            for (int it = 0; it < 8; it++) {
                int idx = it * 512 + tid;
                int row = idx >> 4, g = idx & 15;
                int midx = m0 + row, bb = midx >> 11, ss = midx & 2047;
                int j0 = g * 8;
                int lowh = (j0 < 64) ? 1 : 0;
                int f0 = lowh ? j0 : j0 - 64;
                float o[8];
#pragma unroll
                for (int e = 0; e < 8; e++) {
                    float cs = cosT[ss * 64 + f0 + e];
                    float sn = sinT[ss * 64 + f0 + e];
                    float a = Ct[row * 128 + j0 + e];
                    float p = Ct[row * 128 + (lowh ? j0 + e + 64 : j0 + e - 64)];
                    float v = lowh ? (a * cs - p * sn) : (a * cs + p * sn);
                    o[e] = v > 0.f ? v + 1.f : expf(v);
                }
                uint4 hi, lo;
                pack8(o, hi, lo);
                char* dst = basep + ((size_t)bb * bstride + (size_t)hh * S_ + ss) * 512 + g * 32;
                *(uint4*)dst        = hi;
                *(uint4*)(dst + 16) = lo;
            }
        } else {
            // v head: fp32 rows to vv
            const int kvh = (n0 - 2560) >> 7;
#pragma unroll
            for (int it = 0; it < 16; it++) {
                int idx = it * 512 + tid;
                int r = idx >> 5, c4 = idx & 31;
                int midx = m0 + r, bb = midx >> 11, ss = midx & 2047;
                *(float4*)(vvo + ((size_t)(bb * KVH_ + kvh) * S_ + ss) * HD_ + c4 * 4) =
                    *(const float4*)(Ct + r * 128 + c4 * 4);
            }
        }
    }
}

// ------------------------------------------------------------------ vv -> packed V^T
__global__ __launch_bounds__(256) void vt_k(const float* __restrict__ vv,
                                            char* __restrict__ vtpk)
{
    __shared__ __attribute__((aligned(16))) float Vt[CHK_][HD_ + 4];
    int bx = blockIdx.x;               // bkv*16 + st
    int st = bx & 15;
    int bkv = bx >> 4;
    int tid = threadIdx.x;
#pragma unroll
    for (int it = 0; it < 16; it++) {
        int idx = it * 256 + tid;
        int r = idx >> 5, c4 = idx & 31;
        *(float4*)&Vt[r][c4 * 4] =
            *(const float4*)(vv + ((size_t)bkv * S_ + st * CHK_ + r) * HD_ + c4 * 4);
    }
    __syncthreads();
#pragma unroll
    for (int it = 0; it < 2; it++) {
        int t2 = it * 256 + tid;
        int d = t2 & 127, sg = t2 >> 7;
#pragma unroll
        for (int kk = 0; kk < 4; kk++) {
            int kgl = sg * 4 + kk;
            float f[8];
#pragma unroll
            for (int e = 0; e < 8; e++) f[e] = Vt[kgl * 8 + e][d];
            uint4 hi, lo;
            pack8(f, hi, lo);
            char* op = vtpk + (size_t)bkv * 1048576 + (size_t)d * 8192 + (size_t)(st * 16 + kgl) * 32;
            *(uint4*)op        = hi;
            *(uint4*)(op + 16) = lo;
        }
    }
}

// ------------------------------------------------------------------ per-chunk KV summaries (K from packed)
__global__ __launch_bounds__(256) void chunk_kv_k(
    const char* __restrict__ kfpk, const float* __restrict__ vv,
    float* __restrict__ kvc, float* __restrict__ zc)
{
    int bx = blockIdx.x;
    int c = bx % NC_;
    int bkv = bx / NC_;
    const char* kp = kfpk + ((size_t)bkv * S_ + c * CHK_) * 512;
    const float* vp = vv + ((size_t)bkv * S_ + c * CHK_) * HD_;
    __shared__ __attribute__((aligned(16))) float ks[CHK_][HD_ + 4];
    __shared__ __attribute__((aligned(16))) float vs[CHK_][HD_ + 4];
    int tid = threadIdx.x, tx = tid & 15, ty = tid >> 4;
#pragma unroll
    for (int it = 0; it < 8; it++) {
        int idx = it * 256 + tid;
        int r = idx >> 4, kg = idx & 15;
        const uint4* sp = (const uint4*)(kp + (size_t)r * 512 + kg * 32);
        uint4 hi = sp[0], lo = sp[1];
        float* d = &ks[r][kg * 8];
        d[0] = bf2f(hi.x & 0xFFFFu) + bf2f(lo.x & 0xFFFFu);
        d[1] = bf2f(hi.x >> 16)     + bf2f(lo.x >> 16);
        d[2] = bf2f(hi.y & 0xFFFFu) + bf2f(lo.y & 0xFFFFu);
        d[3] = bf2f(hi.y >> 16)     + bf2f(lo.y >> 16);
        d[4] = bf2f(hi.z & 0xFFFFu) + bf2f(lo.z & 0xFFFFu);
        d[5] = bf2f(hi.z >> 16)     + bf2f(lo.z >> 16);
        d[6] = bf2f(hi.w & 0xFFFFu) + bf2f(lo.w & 0xFFFFu);
        d[7] = bf2f(hi.w >> 16)     + bf2f(lo.w >> 16);
    }
#pragma unroll
    for (int it = 0; it < 16; it++) {
        int idx = it * 256 + tid;
        int r = idx >> 5, c4 = idx & 31;
        *(float4*)&vs[r][c4 * 4] = *(const float4*)(vp + (size_t)r * HD_ + c4 * 4);
    }
    __syncthreads();
    float acc[8][8];
#pragma unroll
    for (int i = 0; i < 8; i++)
#pragma unroll
        for (int j = 0; j < 8; j++) acc[i][j] = 0.f;
    for (int j = 0; j < CHK_; j++) {
        float a[8], b[8];
        *(float4*)&a[0] = *(const float4*)&ks[j][ty * 8];
        *(float4*)&a[4] = *(const float4*)&ks[j][ty * 8 + 4];
        *(float4*)&b[0] = *(const float4*)&vs[j][tx * 8];
        *(float4*)&b[4] = *(const float4*)&vs[j][tx * 8 + 4];
#pragma unroll
        for (int i = 0; i < 8; i++)
#pragma unroll
            for (int jj = 0; jj < 8; jj++)
                acc[i][jj] = fmaf(a[i], b[jj], acc[i][jj]);
    }
    float* outp = kvc + (size_t)bx * (HD_ * HD_);
#pragma unroll
    for (int i = 0; i < 8; i++) {
        float* op = outp + (size_t)(ty * 8 + i) * HD_ + tx * 8;
        *(float4*)op       = make_float4(acc[i][0], acc[i][1], acc[i][2], acc[i][3]);
        *(float4*)(op + 4) = make_float4(acc[i][4], acc[i][5], acc[i][6], acc[i][7]);
    }
    if (tid < CHK_) {
        float z = 0.f;
        for (int j = 0; j < CHK_; j++) z += ks[j][tid];
        zc[(size_t)bx * HD_ + tid] = z;
    }
}

// ------------------------------------------------------------------ exclusive chunk scan
__global__ __launch_bounds__(256) void chunk_scan_k(const float* __restrict__ kvc,
                                                    char* __restrict__ kvct,
                                                    float* __restrict__ zc)
{
    int bx = blockIdx.x;
    int bkv = bx >> 3, dg = bx & 7;
    int tid = threadIdx.x;
    int d = dg * 16 + (tid & 15);
    int g8 = tid >> 4;
    float acc[8];
#pragma unroll
    for (int i = 0; i < 8; i++) acc[i] = 0.f;
    float zacc = 0.f;
    for (int c = 0; c < NC_; c++) {
        size_t cb = (size_t)(bkv * NC_ + c);
        const float* p = kvc + cb * 16384;
        float cur[8];
#pragma unroll
        for (int i = 0; i < 8; i++) cur[i] = p[(g8 * 8 + i) * 128 + d];
        uint4 hi, lo;
        pack8(acc, hi, lo);
        char* op = kvct + cb * 65536 + (size_t)d * 512 + g8 * 32;
        *(uint4*)op        = hi;
        *(uint4*)(op + 16) = lo;
#pragma unroll
        for (int i = 0; i < 8; i++) acc[i] += cur[i];
        if (tid < 16) {
            float* zp = zc + cb * 128 + dg * 16 + tid;
            float zcur = *zp;
            *zp = zacc;
            zacc += zcur;
        }
    }
}

// ------------------------------------------------------------------ per-chunk output, MFMA bf16x3
__global__ __launch_bounds__(256, 1) void chunk_out_k(
    const char* __restrict__ qfpk, const char* __restrict__ kfpk,
    const char* __restrict__ vtpk, const char* __restrict__ kvct,
    const float* __restrict__ zc, char* __restrict__ attnpk)
{
    __shared__ __attribute__((aligned(16))) char smem[100864];
    char*  stA  = smem;
    char*  stB  = smem + 16384;
    float* Pf   = (float*)(smem + 32768);
    float* zs   = (float*)(smem + 98304);
    float* rsum = (float*)(smem + 98816);
    float* den2 = (float*)(smem + 99840);
    float* den  = (float*)(smem + 100352);

    int bx = blockIdx.x;
    int c = bx & 15, h = (bx >> 4) & 15, b = bx >> 8;
    int kv = h >> 2;
    int bkv = b * KVH_ + kv;
    int bkvc = bkv * NC_ + c;
    const char* Qb  = qfpk + ((size_t)(b * H_ + h) * S_ + c * CHK_) * 512;
    const char* Kb  = kfpk + ((size_t)bkv * S_ + c * CHK_) * 512;
    const char* Vtb = vtpk + (size_t)bkv * 1048576 + (size_t)c * 512;
    const char* Spb = kvct + (size_t)bkvc * 65536;
    const float* zp = zc + (size_t)bkvc * 128;

    int tid = threadIdx.x;
    int lane = tid & 63, wv = tid >> 6;
    int wr = wv >> 1, wc = wv & 1;
    int lrow = lane & 15, lg = lane >> 4, l7 = lane & 7;

    if (tid < 32) *(float4*)(zs + tid * 4) = *(const float4*)(zp + tid * 4);

    const char *qsrc[4], *ksrc[4], *vsrc[4], *ssrc[4];
    char *adst[4], *bdst[4];
#pragma unroll
    for (int i = 0; i < 4; i++) {
        int row = wv * 32 + i * 8 + (lane >> 3);
        int sl = (lane & 7) ^ (row & 7);
        qsrc[i] = Qb  + (size_t)row * 512  + sl * 16;
        ksrc[i] = Kb  + (size_t)row * 512  + sl * 16;
        vsrc[i] = Vtb + (size_t)row * 8192 + sl * 16;
        ssrc[i] = Spb + (size_t)row * 512  + sl * 16;
        adst[i] = stA + wv * 4096 + i * 1024;
        bdst[i] = stB + wv * 4096 + i * 1024;
    }
    int aoffs[4], boffs[4];
#pragma unroll
    for (int f = 0; f < 4; f++) {
        aoffs[f] = (wr * 64 + f * 16 + lrow) * 128 + (((lg << 1) ^ l7) << 4);
        boffs[f] = (wc * 64 + f * 16 + lrow) * 128 + (((lg << 1) ^ l7) << 4);
    }

    // GEMM1: S = Q K^T
    f32x4 acc1[4][4];
#pragma unroll
    for (int i = 0; i < 4; i++)
#pragma unroll
        for (int j = 0; j < 4; j++) acc1[i][j] = (f32x4)(0.f);

    for (int s = 0; s < 4; s++) {
#pragma unroll
        for (int i = 0; i < 4; i++) {
            GLOAD16(qsrc[i] + s * 128, adst[i]);
            GLOAD16(ksrc[i] + s * 128, bdst[i]);
        }
        __syncthreads();
        short8 ah[4], al[4], bh[4], bl[4];
#pragma unroll
        for (int f = 0; f < 4; f++) {
            ah[f] = *(const short8*)(stA + aoffs[f]);
            al[f] = *(const short8*)(stA + (aoffs[f] ^ 16));
            bh[f] = *(const short8*)(stB + boffs[f]);
            bl[f] = *(const short8*)(stB + (boffs[f] ^ 16));
        }
#pragma unroll
        for (int i = 0; i < 4; i++)
#pragma unroll
            for (int j = 0; j < 4; j++) {
                acc1[i][j] = MFMA_B16(ah[i], bh[j], acc1[i][j]);
                acc1[i][j] = MFMA_B16(ah[i], bl[j], acc1[i][j]);
                acc1[i][j] = MFMA_B16(al[i], bh[j], acc1[i][j]);
            }
        __syncthreads();
    }

    // mask + rowsum + P -> LDS
#pragma unroll
    for (int fi = 0; fi < 4; fi++) {
#pragma unroll
        for (int reg = 0; reg < 4; reg++) {
            int i = wr * 64 + fi * 16 + lg * 4 + reg;
            float rsv = 0.f;
#pragma unroll
            for (int fj = 0; fj < 4; fj++) {
                int j = wc * 64 + fj * 16 + lrow;
                float v = (j <= i) ? acc1[fi][fj][reg] : 0.f;
                rsv += v;
                Pf[i * 128 + (((j >> 3) ^ (i & 7)) << 3) + (j & 7)] = v;
            }
#pragma unroll
            for (int m = 1; m < 16; m <<= 1) rsv += __shfl_xor(rsv, m, 64);
            if (lrow == 0) rsum[i * 2 + wc] = rsv;
        }
    }

    // GEMM3: O += Q Sp^T + den2 = Q.zp
    f32x4 acc2[4][4];
#pragma unroll
    for (int i = 0; i < 4; i++)
#pragma unroll
        for (int j = 0; j < 4; j++) acc2[i][j] = (f32x4)(0.f);
    float d2a[4] = {0.f, 0.f, 0.f, 0.f};

    for (int s = 0; s < 4; s++) {
#pragma unroll
        for (int i = 0; i < 4; i++) {
            GLOAD16(qsrc[i] + s * 128, adst[i]);
            GLOAD16(ssrc[i] + s * 128, bdst[i]);
        }
        __syncthreads();
        short8 ah[4], al[4], bh[4], bl[4];
#pragma unroll
        for (int f = 0; f < 4; f++) {
            ah[f] = *(const short8*)(stA + aoffs[f]);
            al[f] = *(const short8*)(stA + (aoffs[f] ^ 16));
            bh[f] = *(const short8*)(stB + boffs[f]);
            bl[f] = *(const short8*)(stB + (boffs[f] ^ 16));
        }
        float zv[8];
#pragma unroll
        for (int e = 0; e < 8; e++) zv[e] = zs[s * 32 + lg * 8 + e];
#pragma unroll
        for (int f = 0; f < 4; f++)
#pragma unroll
            for (int e = 0; e < 8; e++)
                d2a[f] += (bf2f((unsigned int)(unsigned short)ah[f][e]) +
                           bf2f((unsigned int)(unsigned short)al[f][e])) * zv[e];
#pragma unroll
        for (int i = 0; i < 4; i++)
#pragma unroll
            for (int j = 0; j < 4; j++) {
                acc2[i][j] = MFMA_B16(ah[i], bh[j], acc2[i][j]);
                acc2[i][j] = MFMA_B16(ah[i], bl[j], acc2[i][j]);
                acc2[i][j] = MFMA_B16(al[i], bh[j], acc2[i][j]);
            }
        __syncthreads();
    }
#pragma unroll
    for (int f = 0; f < 4; f++) {
        float v = d2a[f];
        v += __shfl_xor(v, 16, 64);
        v += __shfl_xor(v, 32, 64);
        if (wc == 0 && lg == 0) den2[wr * 64 + f * 16 + lrow] = v;
    }

    // GEMM2: O += tril(S) V
    for (int s = 0; s < 4; s++) {
#pragma unroll
        for (int i = 0; i < 4; i++) GLOAD16(vsrc[i] + s * 128, bdst[i]);
        __syncthreads();
        short8 ph[4], pl[4], bh[4], bl[4];
#pragma unroll
        for (int f = 0; f < 4; f++) {
            int i = wr * 64 + f * 16 + lrow;
            int g = (s * 4 + lg) ^ (i & 7);
            float pv[8];
            *(float4*)&pv[0] = *(const float4*)(Pf + i * 128 + g * 8);
            *(float4*)&pv[4] = *(const float4*)(Pf + i * 128 + g * 8 + 4);
            split8_frag(pv, ph[f], pl[f]);
            bh[f] = *(const short8*)(stB + boffs[f]);
            bl[f] = *(const short8*)(stB + (boffs[f] ^ 16));
        }
#pragma unroll
        for (int i = 0; i < 4; i++)
#pragma unroll
            for (int j = 0; j < 4; j++) {
                acc2[i][j] = MFMA_B16(ph[i], bh[j], acc2[i][j]);
                acc2[i][j] = MFMA_B16(ph[i], bl[j], acc2[i][j]);
                acc2[i][j] = MFMA_B16(pl[i], bh[j], acc2[i][j]);
            }
        __syncthreads();
    }

    // epilogue: den combine, divide, repack
    if (tid < 128) den[tid] = rsum[tid * 2] + rsum[tid * 2 + 1] + den2[tid] + EPS_;
    __syncthreads();
#pragma unroll
    for (int fi = 0; fi < 4; fi++) {
#pragma unroll
        for (int reg = 0; reg < 4; reg++) {
            int i = wr * 64 + fi * 16 + lg * 4 + reg;
            float inv = 1.0f / den[i];
#pragma unroll
            for (int fd = 0; fd < 4; fd++) {
                int d = wc * 64 + fd * 16 + lrow;
                Pf[i * 128 + (((d >> 3) ^ (i & 7)) << 3) + (d & 7)] = acc2[fi][fd][reg] * inv;
            }
        }
    }
    __syncthreads();
    int s0 = c * CHK_;
#pragma unroll
    for (int it = 0; it < 8; it++) {
        int idx = it * 256 + tid;
        int row = idx >> 4, kg = idx & 15;
        int g = kg ^ (row & 7);
        float f[8];
        *(float4*)&f[0] = *(const float4*)(Pf + row * 128 + g * 8);
        *(float4*)&f[4] = *(const float4*)(Pf + row * 128 + g * 8 + 4);
        uint4 hi, lo;
        pack8(f, hi, lo);
        char* op = attnpk + ((size_t)(b * S_ + s0 + row) * 256 + h * 16 + kg) * 32;
        *(uint4*)op        = hi;
        *(uint4*)(op + 16) = lo;
    }
}

// ------------------------------------------------------------------ launch
// ws layout (floats), total 27,541,504 = 110.17 MB (proven footprint) — identical to R6.
extern "C" void kernel_launch(void* const* d_in, const int* in_sizes, int n_in,
                              void* d_out, int out_size, void* d_ws, size_t ws_size,
                              hipStream_t stream)
{
    (void)in_sizes; (void)n_in; (void)out_size; (void)ws_size;
    const float* x  = (const float*)d_in[0];
    const float* Wq = (const float*)d_in[1];
    const float* Wk = (const float*)d_in[2];
    const float* Wv = (const float*)d_in[3];
    const float* Wo = (const float*)d_in[4];
    float* out = (float*)d_out;
    float* ws  = (float*)d_ws;

    float* xpk   = ws;
    float* wqpk  = ws + 8388608;
    float* wkpk  = ws + 12582912;
    float* wvpk  = ws + 13631488;
    char*  qfpk  = (char*)(ws + 14680064);
    char*  kfpk  = (char*)(ws + 23068672);
    float* vv    = ws + 25165824;
    float* cost  = ws + 27262976;
    float* sint  = ws + 27394048;
    float* zc    = ws + 27525120;
    // post-gemm aliases
    char*  vtpk   = (char*)(ws + 8388608);
    float* kvc    = ws + 10485760;
    char*  kvct   = (char*)(ws + 12582912);
    char*  attnpk = (char*)ws;
    float* wopk   = ws + 8388608;

    rope_tables_k<<<512, 256, 0, stream>>>(cost, sint);

    // phase A: pack x|Wq|Wk|Wv, fused QKV GEMM (M=4096, N=3072, K=2048)
    split_in_k<<<7168, 256, 0, stream>>>(x, Wq, Wk, Wv,
                                         (unsigned int*)xpk, (unsigned int*)wqpk,
                                         (unsigned int*)wkpk, (unsigned int*)wvpk);
    gemm8_k<1><<<384, 512, 0, stream>>>((const char*)xpk, (const char*)wqpk,
                                        (const char*)wkpk, (const char*)wvpk,
                                        nullptr, 0, 2048, 2560, 24,
                                        cost, sint, qfpk, kfpk, vv);

    // phase B: packed V^T from vv
    vt_k<<<128, 256, 0, stream>>>(vv, vtpk);

    // phase C: chunked linear attention (MFMA)
    chunk_kv_k<<<B_ * KVH_ * NC_, 256, 0, stream>>>(kfpk, vv, kvc, zc);
    chunk_scan_k<<<64, 256, 0, stream>>>(kvc, kvct, zc);
    chunk_out_k<<<B_ * H_ * NC_, 256, 0, stream>>>(qfpk, kfpk, vtpk, kvct, zc, attnpk);

    // phase D: pack Wo, O projection (M=4096, N=2048, K=2048)
    split_k<<<2048, 256, 0, stream>>>(Wo, (unsigned int*)wopk, 524288);
    gemm8_k<0><<<256, 512, 0, stream>>>((const char*)attnpk, (const char*)wopk,
                                        (const char*)wopk, (const char*)wopk,
                                        out, 2048, 1 << 30, 1 << 30, 16,
                                        nullptr, nullptr, nullptr, nullptr, nullptr);
}

// Round 9
// 417.990 us; speedup vs baseline: 1.1217x; 1.1217x over previous
//
#include <hip/hip_runtime.h>
#include <math.h>
#include <stdint.h>

#define B_ 2
#define S_ 2048
#define H_ 16
#define KVH_ 4
#define HD_ 128
#define NC_ 16
#define CHK_ 128
#define EPS_ 1e-6f
#define GK_ 2048          // K dim of both big GEMMs
#define NT_ (GK_ / 32)    // K-tiles of 32

typedef __attribute__((ext_vector_type(8))) short short8;   // 8 bf16 (4 VGPR)
typedef __attribute__((ext_vector_type(4))) float f32x4;

// async global->LDS, 16B per lane; LDS dst wave-uniform base + lane*16
#define GLOAD16(gsrc, sdst) \
    __builtin_amdgcn_global_load_lds((const __attribute__((address_space(1))) unsigned int*)(gsrc), \
                                     (__attribute__((address_space(3))) unsigned int*)(sdst), 16, 0, 0)

#define MFMA_B16(a, b, c) __builtin_amdgcn_mfma_f32_16x16x32_bf16((a), (b), (c), 0, 0, 0)

static __device__ __forceinline__ float bf2f(unsigned int u) {
    return __uint_as_float(u << 16);
}

// 8 fp32 -> hi/lo bf16 uint4 pair (truncation split, residual exact)
static __device__ __forceinline__ void pack8(const float* v, uint4& hi, uint4& lo) {
    unsigned int h[4], l[4];
#pragma unroll
    for (int w = 0; w < 4; w++) {
        unsigned int b0 = __float_as_uint(v[2 * w]);
        unsigned int b1 = __float_as_uint(v[2 * w + 1]);
        unsigned int h0 = b0 & 0xFFFF0000u, h1 = b1 & 0xFFFF0000u;
        h[w] = (h0 >> 16) | h1;
        float r0 = v[2 * w] - __uint_as_float(h0);
        float r1 = v[2 * w + 1] - __uint_as_float(h1);
        l[w] = (__float_as_uint(r0) >> 16) | (__float_as_uint(r1) & 0xFFFF0000u);
    }
    hi = make_uint4(h[0], h[1], h[2], h[3]);
    lo = make_uint4(l[0], l[1], l[2], l[3]);
}

// 8 fp32 -> hi/lo short8 MFMA fragments
static __device__ __forceinline__ void split8_frag(const float* p, short8& hi, short8& lo) {
#pragma unroll
    for (int e = 0; e < 8; e++) {
        unsigned int b = __float_as_uint(p[e]);
        unsigned int h = b & 0xFFFF0000u;
        hi[e] = (short)(h >> 16);
        float r = p[e] - __uint_as_float(h);
        lo[e] = (short)(__float_as_uint(r) >> 16);
    }
}

// ------------------------------------------------------------------ fused input packer + RoPE tables
// grid 7680: [0,1835008) pack groups for x|Wq|Wk|Wv, [1835008,1966080) cos/sin tables
__global__ __launch_bounds__(256) void split_in_k(
    const float* __restrict__ x,  const float* __restrict__ wq,
    const float* __restrict__ wk, const float* __restrict__ wv,
    unsigned int* __restrict__ xpk,  unsigned int* __restrict__ wqpk,
    unsigned int* __restrict__ wkpk, unsigned int* __restrict__ wvpk,
    float* __restrict__ cost, float* __restrict__ sint)
{
    int g = blockIdx.x * 256 + threadIdx.x;
    if (g >= 1835008) {
        int idx = g - 1835008;             // S_*64
        int j = idx & 63;
        int s = idx >> 6;
        float inv_freq = powf(10000.0f, -(float)(2 * j) / 128.0f);
        float f = (float)s * inv_freq;
        cost[idx] = cosf(f);
        sint[idx] = sinf(f);
        return;
    }
    const float* in;
    unsigned int* outp;
    int lg;
    if (g < 1048576)      { in = x;  outp = xpk;  lg = g; }
    else if (g < 1572864) { in = wq; outp = wqpk; lg = g - 1048576; }
    else if (g < 1703936) { in = wk; outp = wkpk; lg = g - 1572864; }
    else                  { in = wv; outp = wvpk; lg = g - 1703936; }
    const float* p = in + (size_t)lg * 8;
    float v[8];
    *(float4*)&v[0] = *(const float4*)p;
    *(float4*)&v[4] = *(const float4*)(p + 4);
    uint4 hi, lo;
    pack8(v, hi, lo);
    unsigned int* op = outp + (size_t)lg * 8;
    *(uint4*)op       = hi;
    *(uint4*)(op + 4) = lo;
}

// ------------------------------------------------------------------ plain packer (Wo)
__global__ __launch_bounds__(256) void split_k(const float* __restrict__ in,
                                               unsigned int* __restrict__ outp, int ngrp)
{
    int g = blockIdx.x * 256 + threadIdx.x;
    if (g >= ngrp) return;
    const float* p = in + (size_t)g * 8;
    float x[8];
    *(float4*)&x[0] = *(const float4*)p;
    *(float4*)&x[4] = *(const float4*)(p + 4);
    uint4 hi, lo;
    pack8(x, hi, lo);
    unsigned int* op = outp + (size_t)g * 8;
    *(uint4*)op       = hi;
    *(uint4*)(op + 4) = lo;
}

// ------------------------------------------------------------------ bf16x3 MFMA GEMM (proven R6 structure)
// Y[m,n] = sum_k A[m,k] W[n,k], packed hi/lo inputs (rowbytes = K*4).
// 128x128 tile, BK=32, 4 waves, dbuf LDS 64KB, 2 blocks/CU.
// EPI=0: fp32 store. EPI=1: fused QKV epilogue (RoPE+elu+pack / vv store).
template <int EPI>
__global__ __launch_bounds__(256, 2) void gemm3_k(
    const char* __restrict__ Apk, const char* __restrict__ W0,
    const char* __restrict__ W1, const char* __restrict__ W2,
    float* __restrict__ Y, int ldY, int nend0, int nend1, int nbx,
    const float* __restrict__ cosT, const float* __restrict__ sinT,
    char* __restrict__ qfo, char* __restrict__ kfo, float* __restrict__ vvo)
{
    __shared__ __attribute__((aligned(16))) char smem[65536];

    int nwg = gridDim.x;
    int bid = blockIdx.x;
    int swz = (bid & 7) * (nwg >> 3) + (bid >> 3);
    int by = swz / nbx, bx = swz % nbx;
    const int m0 = by * 128, n0 = bx * 128;

    const char* Wsel;
    int nw;
    if (n0 < nend0)      { Wsel = W0; nw = n0; }
    else if (n0 < nend1) { Wsel = W1; nw = n0 - nend0; }
    else                 { Wsel = W2; nw = n0 - nend1; }

    const int tid = threadIdx.x;
    const int lane = tid & 63;
    const int wv = tid >> 6;
    const int wr = wv >> 1, wc = wv & 1;

    const int r8 = lane >> 3, sl = lane & 7;
    const char* ap[4];
    const char* wp[4];
    int adst[4], wdst[4];
#pragma unroll
    for (int i = 0; i < 4; i++) {
        int rowA = wv * 32 + i * 8 + r8;
        ap[i] = Apk + (size_t)(m0 + rowA) * (GK_ * 4) + (size_t)((sl ^ (rowA & 7)) * 16);
        wp[i] = Wsel + (size_t)(nw + rowA) * (GK_ * 4) + (size_t)((sl ^ (rowA & 7)) * 16);
        adst[i] = wv * 4096 + i * 1024;
        wdst[i] = 16384 + wv * 4096 + i * 1024;
    }

    const int lrow = lane & 15, lg = lane >> 4, lc7 = lane & 7;
    const int aoff = (wr * 64 + lrow) * 128 + ((((lg << 1)) ^ lc7) << 4);
    const int woff = 16384 + (wc * 64 + lrow) * 128 + ((((lg << 1)) ^ lc7) << 4);

    f32x4 acc[4][4];
#pragma unroll
    for (int i = 0; i < 4; i++)
#pragma unroll
        for (int j = 0; j < 4; j++) acc[i][j] = (f32x4)(0.f);

#pragma unroll
    for (int i = 0; i < 4; i++) {
        GLOAD16(ap[i], smem + adst[i]);
        GLOAD16(wp[i], smem + wdst[i]);
    }
    __syncthreads();

    for (int kt = 0; kt < NT_; ++kt) {
        const int cur = kt & 1;
        if (kt + 1 < NT_) {
            const size_t koff = (size_t)(kt + 1) * 128;
            const int nb = (cur ^ 1) * 32768;
#pragma unroll
            for (int i = 0; i < 4; i++) {
                GLOAD16(ap[i] + koff, smem + nb + adst[i]);
                GLOAD16(wp[i] + koff, smem + nb + wdst[i]);
            }
        }
        const char* sb = smem + cur * 32768;
        short8 ah[4], al[4], bh[4], bl[4];
#pragma unroll
        for (int f = 0; f < 4; f++) {
            ah[f] = *(const short8*)(sb + (aoff)        + f * 2048);
            al[f] = *(const short8*)(sb + (aoff ^ 16)   + f * 2048);
            bh[f] = *(const short8*)(sb + (woff)        + f * 2048);
            bl[f] = *(const short8*)(sb + (woff ^ 16)   + f * 2048);
        }
#pragma unroll
        for (int i = 0; i < 4; i++)
#pragma unroll
            for (int j = 0; j < 4; j++) {
                acc[i][j] = MFMA_B16(ah[i], bh[j], acc[i][j]);
                acc[i][j] = MFMA_B16(ah[i], bl[j], acc[i][j]);
                acc[i][j] = MFMA_B16(al[i], bh[j], acc[i][j]);
            }
        __syncthreads();
    }

    if (EPI == 0) {
        // plain fp32 store; C/D layout col = lane&15, row = (lane>>4)*4 + reg
#pragma unroll
        for (int i = 0; i < 4; i++) {
            int r0 = m0 + wr * 64 + i * 16 + lg * 4;
#pragma unroll
            for (int j = 0; j < 4; j++) {
                int cc = n0 + wc * 64 + j * 16 + lrow;
                f32x4 v = acc[i][j];
                Y[(size_t)(r0 + 0) * ldY + cc] = v[0];
                Y[(size_t)(r0 + 1) * ldY + cc] = v[1];
                Y[(size_t)(r0 + 2) * ldY + cc] = v[2];
                Y[(size_t)(r0 + 3) * ldY + cc] = v[3];
            }
        }
    } else {
        // fused QKV epilogue: C tile -> LDS (staging dead after final barrier)
        float* Ct = (float*)smem;      // [128][128] fp32 = 64KB
#pragma unroll
        for (int i = 0; i < 4; i++) {
            int r = wr * 64 + i * 16 + lg * 4;
#pragma unroll
            for (int j = 0; j < 4; j++) {
                int ccol = wc * 64 + j * 16 + lrow;
#pragma unroll
                for (int rr = 0; rr < 4; rr++)
                    Ct[(r + rr) * 128 + ccol] = acc[i][j][rr];
            }
        }
        __syncthreads();
        if (n0 < 2560) {
            // q or k head: RoPE + elu(+1) + pack hi/lo
            const int isq = (n0 < 2048) ? 1 : 0;
            const int hh = isq ? (n0 >> 7) : ((n0 - 2048) >> 7);
            char* basep = isq ? qfo : kfo;
            const int bstride = (isq ? H_ : KVH_) * S_;
#pragma unroll
            for (int it = 0; it < 8; it++) {
                int idx = it * 256 + tid;
                int row = idx >> 4, g = idx & 15;
                int midx = m0 + row, bb = midx >> 11, ss = midx & 2047;
                int j0 = g * 8;
                int lowh = (j0 < 64) ? 1 : 0;
                int f0 = lowh ? j0 : j0 - 64;
                float o[8];
#pragma unroll
                for (int e = 0; e < 8; e++) {
                    float cs = cosT[ss * 64 + f0 + e];
                    float sn = sinT[ss * 64 + f0 + e];
                    float a = Ct[row * 128 + j0 + e];
                    float p = Ct[row * 128 + (lowh ? j0 + e + 64 : j0 + e - 64)];
                    float v = lowh ? (a * cs - p * sn) : (a * cs + p * sn);
                    o[e] = v > 0.f ? v + 1.f : expf(v);
                }
                uint4 hi, lo;
                pack8(o, hi, lo);
                char* dst = basep + ((size_t)bb * bstride + (size_t)hh * S_ + ss) * 512 + g * 32;
                *(uint4*)dst        = hi;
                *(uint4*)(dst + 16) = lo;
            }
        } else {
            // v head: fp32 rows to vv
            const int kvh = (n0 - 2560) >> 7;
#pragma unroll
            for (int it = 0; it < 16; it++) {
                int idx = it * 256 + tid;
                int r = idx >> 5, c4 = idx & 31;
                int midx = m0 + r, bb = midx >> 11, ss = midx & 2047;
                *(float4*)(vvo + ((size_t)(bb * KVH_ + kvh) * S_ + ss) * HD_ + c4 * 4) =
                    *(const float4*)(Ct + r * 128 + c4 * 4);
            }
        }
    }
}

// ------------------------------------------------------------------ fused per-chunk KV summary + V^T pack
// 256 blocks: ((bkv*16 + c)*2 + eh); eh selects 64 e-cols of kvc.
// Both halves write their zc half; eh==1 additionally writes vtpk for (bkv,c).
__global__ __launch_bounds__(256) void chunk_kvt_k(
    const char* __restrict__ kfpk, const float* __restrict__ vv,
    float* __restrict__ kvc, float* __restrict__ zc, char* __restrict__ vtpk)
{
    int bx = blockIdx.x;
    int eh = bx & 1;
    int c = (bx >> 1) & 15;
    int bkv = bx >> 5;
    const char* kp = kfpk + ((size_t)bkv * S_ + c * CHK_) * 512;
    const float* vp = vv + ((size_t)bkv * S_ + c * CHK_) * HD_;
    __shared__ __attribute__((aligned(16))) float ks[CHK_][68];       // this block's 64 e-cols
    __shared__ __attribute__((aligned(16))) float vs[CHK_][HD_ + 4];
    int tid = threadIdx.x, tx = tid & 15, ty = tid >> 4;
#pragma unroll
    for (int it = 0; it < 4; it++) {       // 128 rows x 8 kgroups (this e-half)
        int idx = it * 256 + tid;
        int r = idx >> 3, kg8 = idx & 7;
        const uint4* sp = (const uint4*)(kp + (size_t)r * 512 + (eh * 8 + kg8) * 32);
        uint4 hi = sp[0], lo = sp[1];
        float* d = &ks[r][kg8 * 8];
        d[0] = bf2f(hi.x & 0xFFFFu) + bf2f(lo.x & 0xFFFFu);
        d[1] = bf2f(hi.x >> 16)     + bf2f(lo.x >> 16);
        d[2] = bf2f(hi.y & 0xFFFFu) + bf2f(lo.y & 0xFFFFu);
        d[3] = bf2f(hi.y >> 16)     + bf2f(lo.y >> 16);
        d[4] = bf2f(hi.z & 0xFFFFu) + bf2f(lo.z & 0xFFFFu);
        d[5] = bf2f(hi.z >> 16)     + bf2f(lo.z >> 16);
        d[6] = bf2f(hi.w & 0xFFFFu) + bf2f(lo.w & 0xFFFFu);
        d[7] = bf2f(hi.w >> 16)     + bf2f(lo.w >> 16);
    }
#pragma unroll
    for (int it = 0; it < 16; it++) {
        int idx = it * 256 + tid;
        int r = idx >> 5, c4 = idx & 31;
        *(float4*)&vs[r][c4 * 4] = *(const float4*)(vp + (size_t)r * HD_ + c4 * 4);
    }
    __syncthreads();
    // acc: e = eh*64 + ty*4 + i (4 rows), d = tx*8 + jj (8 cols)
    float acc[4][8];
#pragma unroll
    for (int i = 0; i < 4; i++)
#pragma unroll
        for (int j = 0; j < 8; j++) acc[i][j] = 0.f;
    for (int j = 0; j < CHK_; j++) {
        float a[4], b[8];
        *(float4*)&a[0] = *(const float4*)&ks[j][ty * 4];
        *(float4*)&b[0] = *(const float4*)&vs[j][tx * 8];
        *(float4*)&b[4] = *(const float4*)&vs[j][tx * 8 + 4];
#pragma unroll
        for (int i = 0; i < 4; i++)
#pragma unroll
            for (int jj = 0; jj < 8; jj++)
                acc[i][jj] = fmaf(a[i], b[jj], acc[i][jj]);
    }
    float* outp = kvc + (size_t)(bkv * NC_ + c) * (HD_ * HD_);
#pragma unroll
    for (int i = 0; i < 4; i++) {
        float* op = outp + (size_t)(eh * 64 + ty * 4 + i) * HD_ + tx * 8;
        *(float4*)op       = make_float4(acc[i][0], acc[i][1], acc[i][2], acc[i][3]);
        *(float4*)(op + 4) = make_float4(acc[i][4], acc[i][5], acc[i][6], acc[i][7]);
    }
    if (tid < 64) {        // z for this e-half
        float z = 0.f;
        for (int j = 0; j < CHK_; j++) z += ks[j][tid];
        zc[(size_t)(bkv * NC_ + c) * HD_ + eh * 64 + tid] = z;
    }
    if (eh == 1) {         // V^T pack for this (bkv, st=c)
#pragma unroll
        for (int it = 0; it < 2; it++) {
            int t2 = it * 256 + tid;
            int d = t2 & 127, sg = t2 >> 7;
#pragma unroll
            for (int kk = 0; kk < 4; kk++) {
                int kgl = sg * 4 + kk;
                float f[8];
#pragma unroll
                for (int e = 0; e < 8; e++) f[e] = vs[kgl * 8 + e][d];
                uint4 hi, lo;
                pack8(f, hi, lo);
                char* op = vtpk + (size_t)bkv * 1048576 + (size_t)d * 8192 + (size_t)(c * 16 + kgl) * 32;
                *(uint4*)op        = hi;
                *(uint4*)(op + 16) = lo;
            }
        }
    }
}

// ------------------------------------------------------------------ exclusive chunk scan
// 64 blocks (bkv x dgroup). Emits packed-transposed exclusive prefix
// kvcT[bkvc][d=128 rows][16 e-kgroups x 32B]; zc prefix in place (fp32).
__global__ __launch_bounds__(256) void chunk_scan_k(const float* __restrict__ kvc,
                                                    char* __restrict__ kvct,
                                                    float* __restrict__ zc)
{
    int bx = blockIdx.x;
    int bkv = bx >> 3, dg = bx & 7;
    int tid = threadIdx.x;
    int d = dg * 16 + (tid & 15);
    int g8 = tid >> 4;                 // e-kgroup 0..15
    float acc[8];
#pragma unroll
    for (int i = 0; i < 8; i++) acc[i] = 0.f;
    float zacc = 0.f;
    for (int c = 0; c < NC_; c++) {
        size_t cb = (size_t)(bkv * NC_ + c);
        const float* p = kvc + cb * 16384;
        float cur[8];
#pragma unroll
        for (int i = 0; i < 8; i++) cur[i] = p[(g8 * 8 + i) * 128 + d];
        uint4 hi, lo;
        pack8(acc, hi, lo);
        char* op = kvct + cb * 65536 + (size_t)d * 512 + g8 * 32;
        *(uint4*)op        = hi;
        *(uint4*)(op + 16) = lo;
#pragma unroll
        for (int i = 0; i < 8; i++) acc[i] += cur[i];
        if (tid < 16) {
            float* zp = zc + cb * 128 + dg * 16 + tid;
            float zcur = *zp;
            *zp = zacc;
            zacc += zcur;
        }
    }
}

// ------------------------------------------------------------------ per-chunk output, MFMA bf16x3
// O = (tril(Q K^T) V + Q Sp) / (rowsum(tril(Q K^T)) + Q zp + eps); packed hi/lo out.
__global__ __launch_bounds__(256, 1) void chunk_out_k(
    const char* __restrict__ qfpk, const char* __restrict__ kfpk,
    const char* __restrict__ vtpk, const char* __restrict__ kvct,
    const float* __restrict__ zc, char* __restrict__ attnpk)
{
    __shared__ __attribute__((aligned(16))) char smem[100864];
    char*  stA  = smem;                       // 16KB staging (A slab)
    char*  stB  = smem + 16384;               // 16KB staging (B slab)
    float* Pf   = (float*)(smem + 32768);     // 64KB [128][128] fp32, 32B-granule XOR swizzle
    float* zs   = (float*)(smem + 98304);     // 128
    float* rsum = (float*)(smem + 98816);     // 128 x 2 (wc partials)
    float* den2 = (float*)(smem + 99840);     // 128
    float* den  = (float*)(smem + 100352);    // 128

    int bx = blockIdx.x;                      // (b*16+h)*16 + c
    int c = bx & 15, h = (bx >> 4) & 15, b = bx >> 8;
    int kv = h >> 2;
    int bkv = b * KVH_ + kv;
    int bkvc = bkv * NC_ + c;
    const char* Qb  = qfpk + ((size_t)(b * H_ + h) * S_ + c * CHK_) * 512;
    const char* Kb  = kfpk + ((size_t)bkv * S_ + c * CHK_) * 512;
    const char* Vtb = vtpk + (size_t)bkv * 1048576 + (size_t)c * 512;   // + d*8192 + s*128
    const char* Spb = kvct + (size_t)bkvc * 65536;                      // + d*512  + s*128
    const float* zp = zc + (size_t)bkvc * 128;

    int tid = threadIdx.x;
    int lane = tid & 63, wv = tid >> 6;
    int wr = wv >> 1, wc = wv & 1;
    int lrow = lane & 15, lg = lane >> 4, l7 = lane & 7;

    if (tid < 32) *(float4*)(zs + tid * 4) = *(const float4*)(zp + tid * 4);

    const char *qsrc[4], *ksrc[4], *vsrc[4], *ssrc[4];
    char *adst[4], *bdst[4];
#pragma unroll
    for (int i = 0; i < 4; i++) {
        int row = wv * 32 + i * 8 + (lane >> 3);
        int sl = (lane & 7) ^ (row & 7);
        qsrc[i] = Qb  + (size_t)row * 512  + sl * 16;
        ksrc[i] = Kb  + (size_t)row * 512  + sl * 16;
        vsrc[i] = Vtb + (size_t)row * 8192 + sl * 16;
        ssrc[i] = Spb + (size_t)row * 512  + sl * 16;
        adst[i] = stA + wv * 4096 + i * 1024;
        bdst[i] = stB + wv * 4096 + i * 1024;
    }
    int aoffs[4], boffs[4];
#pragma unroll
    for (int f = 0; f < 4; f++) {
        aoffs[f] = (wr * 64 + f * 16 + lrow) * 128 + (((lg << 1) ^ l7) << 4);
        boffs[f] = (wc * 64 + f * 16 + lrow) * 128 + (((lg << 1) ^ l7) << 4);
    }

    // ---------------- GEMM1: S = Q K^T ----------------
    f32x4 acc1[4][4];
#pragma unroll
    for (int i = 0; i < 4; i++)
#pragma unroll
        for (int j = 0; j < 4; j++) acc1[i][j] = (f32x4)(0.f);

    for (int s = 0; s < 4; s++) {
#pragma unroll
        for (int i = 0; i < 4; i++) {
            GLOAD16(qsrc[i] + s * 128, adst[i]);
            GLOAD16(ksrc[i] + s * 128, bdst[i]);
        }
        __syncthreads();
        short8 ah[4], al[4], bh[4], bl[4];
#pragma unroll
        for (int f = 0; f < 4; f++) {
            ah[f] = *(const short8*)(stA + aoffs[f]);
            al[f] = *(const short8*)(stA + (aoffs[f] ^ 16));
            bh[f] = *(const short8*)(stB + boffs[f]);
            bl[f] = *(const short8*)(stB + (boffs[f] ^ 16));
        }
#pragma unroll
        for (int i = 0; i < 4; i++)
#pragma unroll
            for (int j = 0; j < 4; j++) {
                acc1[i][j] = MFMA_B16(ah[i], bh[j], acc1[i][j]);
                acc1[i][j] = MFMA_B16(ah[i], bl[j], acc1[i][j]);
                acc1[i][j] = MFMA_B16(al[i], bh[j], acc1[i][j]);
            }
        __syncthreads();
    }

    // ---------------- mask + rowsum + P -> LDS ----------------
#pragma unroll
    for (int fi = 0; fi < 4; fi++) {
#pragma unroll
        for (int reg = 0; reg < 4; reg++) {
            int i = wr * 64 + fi * 16 + lg * 4 + reg;
            float rsv = 0.f;
#pragma unroll
            for (int fj = 0; fj < 4; fj++) {
                int j = wc * 64 + fj * 16 + lrow;
                float v = (j <= i) ? acc1[fi][fj][reg] : 0.f;
                rsv += v;
                Pf[i * 128 + (((j >> 3) ^ (i & 7)) << 3) + (j & 7)] = v;
            }
#pragma unroll
            for (int m = 1; m < 16; m <<= 1) rsv += __shfl_xor(rsv, m, 64);
            if (lrow == 0) rsum[i * 2 + wc] = rsv;
        }
    }

    // ---------------- GEMM3: O += Q Sp^T + den2 = Q.zp ----------------
    f32x4 acc2[4][4];
#pragma unroll
    for (int i = 0; i < 4; i++)
#pragma unroll
        for (int j = 0; j < 4; j++) acc2[i][j] = (f32x4)(0.f);
    float d2a[4] = {0.f, 0.f, 0.f, 0.f};

    for (int s = 0; s < 4; s++) {
#pragma unroll
        for (int i = 0; i < 4; i++) {
            GLOAD16(qsrc[i] + s * 128, adst[i]);
            GLOAD16(ssrc[i] + s * 128, bdst[i]);
        }
        __syncthreads();
        short8 ah[4], al[4], bh[4], bl[4];
#pragma unroll
        for (int f = 0; f < 4; f++) {
            ah[f] = *(const short8*)(stA + aoffs[f]);
            al[f] = *(const short8*)(stA + (aoffs[f] ^ 16));
            bh[f] = *(const short8*)(stB + boffs[f]);
            bl[f] = *(const short8*)(stB + (boffs[f] ^ 16));
        }
        float zv[8];
#pragma unroll
        for (int e = 0; e < 8; e++) zv[e] = zs[s * 32 + lg * 8 + e];
#pragma unroll
        for (int f = 0; f < 4; f++)
#pragma unroll
            for (int e = 0; e < 8; e++)
                d2a[f] += (bf2f((unsigned int)(unsigned short)ah[f][e]) +
                           bf2f((unsigned int)(unsigned short)al[f][e])) * zv[e];
#pragma unroll
        for (int i = 0; i < 4; i++)
#pragma unroll
            for (int j = 0; j < 4; j++) {
                acc2[i][j] = MFMA_B16(ah[i], bh[j], acc2[i][j]);
                acc2[i][j] = MFMA_B16(ah[i], bl[j], acc2[i][j]);
                acc2[i][j] = MFMA_B16(al[i], bh[j], acc2[i][j]);
            }
        __syncthreads();
    }
#pragma unroll
    for (int f = 0; f < 4; f++) {
        float v = d2a[f];
        v += __shfl_xor(v, 16, 64);
        v += __shfl_xor(v, 32, 64);
        if (wc == 0 && lg == 0) den2[wr * 64 + f * 16 + lrow] = v;
    }

    // ---------------- GEMM2: O += tril(S) V ----------------
    for (int s = 0; s < 4; s++) {
#pragma unroll
        for (int i = 0; i < 4; i++) GLOAD16(vsrc[i] + s * 128, bdst[i]);
        __syncthreads();
        short8 ph[4], pl[4], bh[4], bl[4];
#pragma unroll
        for (int f = 0; f < 4; f++) {
            int i = wr * 64 + f * 16 + lrow;
            int g = (s * 4 + lg) ^ (i & 7);
            float pv[8];
            *(float4*)&pv[0] = *(const float4*)(Pf + i * 128 + g * 8);
            *(float4*)&pv[4] = *(const float4*)(Pf + i * 128 + g * 8 + 4);
            split8_frag(pv, ph[f], pl[f]);
            bh[f] = *(const short8*)(stB + boffs[f]);
            bl[f] = *(const short8*)(stB + (boffs[f] ^ 16));
        }
#pragma unroll
        for (int i = 0; i < 4; i++)
#pragma unroll
            for (int j = 0; j < 4; j++) {
                acc2[i][j] = MFMA_B16(ph[i], bh[j], acc2[i][j]);
                acc2[i][j] = MFMA_B16(ph[i], bl[j], acc2[i][j]);
                acc2[i][j] = MFMA_B16(pl[i], bh[j], acc2[i][j]);
            }
        __syncthreads();
    }

    // ---------------- epilogue: den combine, divide, repack ----------------
    if (tid < 128) den[tid] = rsum[tid * 2] + rsum[tid * 2 + 1] + den2[tid] + EPS_;
    __syncthreads();
#pragma unroll
    for (int fi = 0; fi < 4; fi++) {
#pragma unroll
        for (int reg = 0; reg < 4; reg++) {
            int i = wr * 64 + fi * 16 + lg * 4 + reg;
            float inv = 1.0f / den[i];
#pragma unroll
            for (int fd = 0; fd < 4; fd++) {
                int d = wc * 64 + fd * 16 + lrow;
                Pf[i * 128 + (((d >> 3) ^ (i & 7)) << 3) + (d & 7)] = acc2[fi][fd][reg] * inv;
            }
        }
    }
    __syncthreads();
    int s0 = c * CHK_;
#pragma unroll
    for (int it = 0; it < 8; it++) {
        int idx = it * 256 + tid;
        int row = idx >> 4, kg = idx & 15;
        int g = kg ^ (row & 7);
        float f[8];
        *(float4*)&f[0] = *(const float4*)(Pf + row * 128 + g * 8);
        *(float4*)&f[4] = *(const float4*)(Pf + row * 128 + g * 8 + 4);
        uint4 hi, lo;
        pack8(f, hi, lo);
        char* op = attnpk + ((size_t)(b * S_ + s0 + row) * 256 + h * 16 + kg) * 32;
        *(uint4*)op        = hi;
        *(uint4*)(op + 16) = lo;
    }
}

// ------------------------------------------------------------------ launch
// ws layout (floats), total 27,541,504 = 110.17 MB (proven footprint), lifetime-aliased:
//   [0,        8388608)  xpk        -> attnpk (xpk dead after gemm<1>)
//   [8388608, 12582912)  wqpk       -> vtpk [8388608,10485760) + kvc [10485760,12582912)
//                                   -> wopk [8388608,12582912) after chunk_out
//   [12582912,14680064)  wkpk+wvpk  -> kvct
//   [14680064,23068672)  qfpk
//   [23068672,25165824)  kfpk
//   [25165824,27262976)  vv
//   [27262976,27525120)  cos | sin
//   [27525120,27541504)  zc
extern "C" void kernel_launch(void* const* d_in, const int* in_sizes, int n_in,
                              void* d_out, int out_size, void* d_ws, size_t ws_size,
                              hipStream_t stream)
{
    (void)in_sizes; (void)n_in; (void)out_size; (void)ws_size;
    const float* x  = (const float*)d_in[0];
    const float* Wq = (const float*)d_in[1];
    const float* Wk = (const float*)d_in[2];
    const float* Wv = (const float*)d_in[3];
    const float* Wo = (const float*)d_in[4];
    float* out = (float*)d_out;
    float* ws  = (float*)d_ws;

    float* xpk   = ws;
    float* wqpk  = ws + 8388608;
    float* wkpk  = ws + 12582912;
    float* wvpk  = ws + 13631488;
    char*  qfpk  = (char*)(ws + 14680064);
    char*  kfpk  = (char*)(ws + 23068672);
    float* vv    = ws + 25165824;
    float* cost  = ws + 27262976;
    float* sint  = ws + 27394048;
    float* zc    = ws + 27525120;
    // post-gemm aliases
    char*  vtpk   = (char*)(ws + 8388608);
    float* kvc    = ws + 10485760;
    char*  kvct   = (char*)(ws + 12582912);
    char*  attnpk = (char*)ws;
    float* wopk   = ws + 8388608;      // over dead vtpk+kvc, split after chunk_out

    // phase A: pack x|Wq|Wk|Wv + RoPE tables (one launch), fused QKV GEMM
    split_in_k<<<7680, 256, 0, stream>>>(x, Wq, Wk, Wv,
                                         (unsigned int*)xpk, (unsigned int*)wqpk,
                                         (unsigned int*)wkpk, (unsigned int*)wvpk,
                                         cost, sint);
    gemm3_k<1><<<768, 256, 0, stream>>>((const char*)xpk, (const char*)wqpk,
                                        (const char*)wkpk, (const char*)wvpk,
                                        nullptr, 0, 2048, 2560, 24,
                                        cost, sint, qfpk, kfpk, vv);

    // phase C: chunked linear attention (MFMA); chunk_kvt also emits packed V^T
    chunk_kvt_k<<<256, 256, 0, stream>>>(kfpk, vv, kvc, zc, vtpk);
    chunk_scan_k<<<64, 256, 0, stream>>>(kvc, kvct, zc);
    chunk_out_k<<<B_ * H_ * NC_, 256, 0, stream>>>(qfpk, kfpk, vtpk, kvct, zc, attnpk);

    // phase D: pack Wo (vtpk/kvc now dead), O projection (M=4096, N=2048, K=2048)
    split_k<<<2048, 256, 0, stream>>>(Wo, (unsigned int*)wopk, 524288);
    gemm3_k<0><<<512, 256, 0, stream>>>((const char*)attnpk, (const char*)wopk,
                                        (const char*)wopk, (const char*)wopk,
                                        out, 2048, 1 << 30, 1 << 30, 16,
                                        nullptr, nullptr, nullptr, nullptr, nullptr);
}